// Round 7
// baseline (270.488 us; speedup 1.0000x reference)
//
#include <hip/hip_runtime.h>

// Sizes (fixed): B=8, S=4096, D=1024, C=256, P=64 -> windows of 64 rows, NBP=512
#define D_  1024
#define C_  256

using bf16x8 = __attribute__((ext_vector_type(8))) __bf16;
using f32x4  = __attribute__((ext_vector_type(4))) float;

__device__ __forceinline__ unsigned short f2bf(float x) {
  unsigned int u = __float_as_uint(x);
  u += 0x7fffu + ((u >> 16) & 1u);
  return (unsigned short)(u >> 16);
}

// ---- fused prep:
//  blocks [0,256):   W_down f32 -> bf16 in MFMA-FRAGMENT order:
//                    byte = (((kt*16 + ch16)*2 + ks)*64 + lg*16 + l15)*16 + j*2
//                    where ch16=ch>>4, l15=ch&15, kt=d>>6, ks=(d>>5)&1, lg=(d>>3)&3, j=d&7.
//                    Lane (lg*16+l15) then loads its B-frag as one dwordx4.
//  blocks [256,320): W_up [1024][256] -> W_upT [256][1024] (LDS transpose)
//  block  320:       zero BN accumulators
__global__ void k_prep(const float* __restrict__ wdown, const float* __restrict__ wup,
                       unsigned short* __restrict__ wdb, float* __restrict__ wupT,
                       float* __restrict__ gsum, float* __restrict__ gsq) {
  int bid = blockIdx.x, tid = threadIdx.x;
  if (bid < 256) {
    int idx = (bid * 256 + tid) * 4;            // 262144 elements, 4 consecutive d
    float4 v = *(const float4*)(wdown + idx);
    int ch = idx >> 10;
    int d  = idx & 1023;
    int kt = d >> 6;
    int ks = (d >> 5) & 1;
    int lg = (d >> 3) & 3;
    int j0 = d & 7;                              // 0 or 4
    int lane = lg * 16 + (ch & 15);
    int grp  = (kt * 16 + (ch >> 4)) * 2 + ks;
    ushort4 o;
    o.x = f2bf(v.x); o.y = f2bf(v.y); o.z = f2bf(v.z); o.w = f2bf(v.w);
    size_t byteoff = ((size_t)grp * 64 + lane) * 16 + j0 * 2;
    *(ushort4*)((char*)wdb + byteoff) = o;
  } else if (bid < 320) {
    __shared__ float t[64][68];
    int b2 = bid - 256;
    int d0 = (b2 >> 2) * 64, c0 = (b2 & 3) * 64;
    #pragma unroll
    for (int r = 0; r < 4; ++r) {
      int idx = r * 256 + tid;
      int dr = idx >> 4, c4 = idx & 15;
      float4 v = *(const float4*)(wup + (d0 + dr) * C_ + c0 + c4 * 4);
      t[dr][c4*4+0] = v.x; t[dr][c4*4+1] = v.y; t[dr][c4*4+2] = v.z; t[dr][c4*4+3] = v.w;
    }
    __syncthreads();
    #pragma unroll
    for (int r = 0; r < 4; ++r) {
      int idx = r * 256 + tid;
      int cr = idx >> 4, d4 = idx & 15;
      float4 v;
      v.x = t[d4*4+0][cr]; v.y = t[d4*4+1][cr]; v.z = t[d4*4+2][cr]; v.w = t[d4*4+3][cr];
      *(float4*)(wupT + (c0 + cr) * D_ + d0 + d4 * 4) = v;
    }
  } else {
    gsum[tid] = 0.f;
    gsq[tid]  = 0.f;
  }
}

// ---- main: down-proj bf16 MFMA. A: reg-prefetched + LDS dbuf (16 KB, XOR-swizzled).
//      B: direct L2->register fragment loads from fragment-ordered wdb (no LDS).
//      One barrier per kt. Windowed max + relu + BN partials in epilogue.
__global__ __launch_bounds__(256, 2)
void k_down_pool(const float* __restrict__ hid, const unsigned short* __restrict__ wdb,
                 const float* __restrict__ bdown, float* __restrict__ pooled,
                 float* __restrict__ gsum, float* __restrict__ gsq) {
  __shared__ unsigned short sA0[4096], sA1[4096];   // 8 KB each: 64 rows x 128B, swizzled
  const int bp   = blockIdx.x;
  const int tid  = threadIdx.x;
  const int lane = tid & 63;
  const int wv   = tid >> 6;        // wave -> 64-channel group
  const int l15  = lane & 15;
  const int lg   = lane >> 4;

  const float* hbase = hid + (size_t)bp * 64 * D_;

  f32x4 acc[4][4] = {};
  float4 areg[4];

  auto loadA = [&](int kt) {
    #pragma unroll
    for (int i = 0; i < 4; ++i) {
      int idx = i * 256 + tid;
      int row = idx >> 4, c4 = idx & 15;
      areg[i] = *(const float4*)(hbase + row * D_ + kt * 64 + c4 * 4);
    }
  };
  auto writeA = [&](unsigned short* sA) {
    #pragma unroll
    for (int i = 0; i < 4; ++i) {
      int idx = i * 256 + tid;
      int row = idx >> 4, c4 = idx & 15;
      ushort4 h;
      h.x = f2bf(areg[i].x); h.y = f2bf(areg[i].y); h.z = f2bf(areg[i].z); h.w = f2bf(areg[i].w);
      int off = row * 128 + ((c4 * 8) ^ ((row & 7) << 4));
      *(ushort4*)((char*)sA + off) = h;
    }
  };
  auto compute = [&](const unsigned short* sA, int kt) {
    // B-frag base for this wave/kt: grp = kt*32 + wv*8 + n*2 + ks, addr = grp*1024 + lane*16
    const char* wb = (const char*)wdb + ((size_t)(kt * 32 + wv * 8) << 10) + lane * 16;
    #pragma unroll
    for (int ks = 0; ks < 2; ++ks) {
      union { uint4 u; bf16x8 v; } b[4];
      #pragma unroll
      for (int n = 0; n < 4; ++n)
        b[n].u = *(const uint4*)(wb + ((n * 2 + ks) << 10));
      bf16x8 afr[4];
      #pragma unroll
      for (int m = 0; m < 4; ++m) {
        int row = m * 16 + l15;
        int off = row * 128 + ((ks * 64 + lg * 16) ^ ((row & 7) << 4));
        union { uint4 u; bf16x8 v; } t;
        t.u = *(const uint4*)((const char*)sA + off);
        afr[m] = t.v;
      }
      #pragma unroll
      for (int n = 0; n < 4; ++n)
        #pragma unroll
        for (int m = 0; m < 4; ++m)
          acc[m][n] = __builtin_amdgcn_mfma_f32_16x16x32_bf16(afr[m], b[n].v, acc[m][n], 0, 0, 0);
    }
  };

  loadA(0);
  writeA(sA0);
  __syncthreads();

  #pragma unroll 1
  for (int kt = 0; kt < 16; ++kt) {
    unsigned short* cur = (kt & 1) ? sA1 : sA0;
    unsigned short* nxt = (kt & 1) ? sA0 : sA1;
    if (kt < 15) loadA(kt + 1);        // in flight across compute
    compute(cur, kt);
    if (kt < 15) writeA(nxt);          // waits on areg deps automatically
    __syncthreads();
  }

  // ---- epilogue: window max + bias + relu + BN partials
  #pragma unroll
  for (int n = 0; n < 4; ++n) {
    float vmax = -__builtin_inff();
    #pragma unroll
    for (int m = 0; m < 4; ++m)
      #pragma unroll
      for (int r = 0; r < 4; ++r)
        vmax = fmaxf(vmax, acc[m][n][r]);
    vmax = fmaxf(vmax, __shfl_xor(vmax, 16, 64));
    vmax = fmaxf(vmax, __shfl_xor(vmax, 32, 64));
    int col = wv * 64 + n * 16 + l15;
    if (lane < 16) {
      float pv = fmaxf(vmax + bdown[col], 0.f);
      pooled[bp * C_ + col] = pv;
      atomicAdd(&gsum[col], pv);
      atomicAdd(&gsq[col],  pv * pv);
    }
  }
}

// ---- up-proj with fused BN finalize: 256 blocks = 64 rgroups x 4 dgroups;
//      block: 8 rows x 256 d; reads only a 256 KB wupT slice (64 MB L2 total)
__global__ __launch_bounds__(256)
void k_up(const float* __restrict__ pooled, const float* __restrict__ wupT,
          const float* __restrict__ gsum, const float* __restrict__ gsq,
          const float* __restrict__ gamma, const float* __restrict__ beta,
          const float* __restrict__ bup, float* __restrict__ out) {
  __shared__ float sx[8][256];
  int tid = threadIdx.x;
  int dg = blockIdx.x & 3;
  int r0 = (blockIdx.x >> 2) * 8;
  float mean = gsum[tid] * (1.f / 512.f);
  float var  = gsq[tid] * (1.f / 512.f) - mean * mean;
  float inv  = 1.f / sqrtf(var + 1e-5f);
  float sc = gamma[tid] * inv;
  float sh = beta[tid] - mean * sc;
  #pragma unroll
  for (int r = 0; r < 8; ++r)
    sx[r][tid] = pooled[(r0 + r) * C_ + tid] * sc + sh;
  __syncthreads();
  int d = dg * 256 + tid;
  float acc[8] = {};
  #pragma unroll 4
  for (int k = 0; k < 256; ++k) {
    float w = wupT[(size_t)k * D_ + d];
    #pragma unroll
    for (int r = 0; r < 8; ++r) acc[r] += sx[r][k] * w;
  }
  float bb = bup[d];
  #pragma unroll
  for (int r = 0; r < 8; ++r)
    out[(size_t)(r0 + r) * D_ + d] = acc[r] + bb;
}

extern "C" void kernel_launch(void* const* d_in, const int* in_sizes, int n_in,
                              void* d_out, int out_size, void* d_ws, size_t ws_size,
                              hipStream_t stream) {
  const float* hid   = (const float*)d_in[0];
  const float* wdown = (const float*)d_in[1];
  const float* bdown = (const float*)d_in[2];
  const float* gamma = (const float*)d_in[3];
  const float* beta  = (const float*)d_in[4];
  const float* wup   = (const float*)d_in[5];
  const float* bup   = (const float*)d_in[6];
  float* out = (float*)d_out;

  char* ws = (char*)d_ws;
  unsigned short* wdb = (unsigned short*)ws;               // 512 KB (fragment-ordered bf16)
  float* wupT   = (float*)(ws + (512 << 10));              // 1 MB
  float* pooled = (float*)(ws + (1536 << 10));             // 512 KB
  float* gsum   = (float*)(ws + (2048 << 10));             // 1 KB
  float* gsq    = (float*)(ws + (2048 << 10) + 1024);      // 1 KB

  hipLaunchKernelGGL(k_prep,      dim3(321), dim3(256), 0, stream, wdown, wup, wdb, wupT, gsum, gsq);
  hipLaunchKernelGGL(k_down_pool, dim3(512), dim3(256), 0, stream, hid, wdb, bdown, pooled, gsum, gsq);
  hipLaunchKernelGGL(k_up,        dim3(256), dim3(256), 0, stream, pooled, wupT, gsum, gsq, gamma, beta, bup, out);
}